// Round 1
// baseline (711.507 us; speedup 1.0000x reference)
//
#include <hip/hip_runtime.h>
#include <cstdint>

typedef unsigned long long u64;

// Problem constants (fixed by setup_inputs): B=2, T=2048, C=1024, H=16, D=64
#define T_LEN 2048
#define C_DIM 1024
#define H_NUM 16
#define M_ROWS 4096  // B*T

// ---------------------------------------------------------------------------
// GEMM: C = A[M][K] * Bt[N][K]^T + bias, N segmented into 1024-col segments
// (segment sel = which of 3 weight/bias/output pointers). 128x128 tile,
// 256 threads, 8x8 register micro-tile, BK=16. LDS stride 132 (16B-aligned,
// breaks power-of-2 bank conflicts to <=2-way on writes, broadcast on A reads).
// ---------------------------------------------------------------------------
__global__ __launch_bounds__(256) void gemm128(
    const float* __restrict__ A,
    const float* B0, const float* B1, const float* B2,
    const float* bias0, const float* bias1, const float* bias2,
    float* C0, float* C1, float* C2, int K)
{
  __shared__ float As[16][132];
  __shared__ float Bs[16][132];
  const int tid = threadIdx.x;
  const int bm  = blockIdx.x * 128;
  const int bng = blockIdx.y * 128;
  const int sel = bng >> 10;        // which 1024-col segment
  const int bn  = bng & 1023;
  const float* Bt   = (sel == 0) ? B0 : (sel == 1) ? B1 : B2;
  const float* bias = (sel == 0) ? bias0 : (sel == 1) ? bias1 : bias2;
  float* C          = (sel == 0) ? C0 : (sel == 1) ? C1 : C2;

  const int rowg = (tid >> 4) << 3;   // 16 row-groups * 8
  const int colg = (tid & 15) << 3;   // 16 col-groups * 8
  const int lrow = tid >> 2;          // staging: row within tile
  const int lc   = (tid & 3) << 2;    // staging: k-offset (float4)

  float acc[8][8];
  #pragma unroll
  for (int i = 0; i < 8; ++i)
    #pragma unroll
    for (int j = 0; j < 8; ++j) acc[i][j] = 0.f;

  for (int kt = 0; kt < K; kt += 16) {
    #pragma unroll
    for (int jj = 0; jj < 2; ++jj) {
      const int row = lrow + jj * 64;
      const float4 av = *(const float4*)&A[(size_t)(bm + row) * K + kt + lc];
      As[lc + 0][row] = av.x; As[lc + 1][row] = av.y;
      As[lc + 2][row] = av.z; As[lc + 3][row] = av.w;
      const float4 bv = *(const float4*)&Bt[(size_t)(bn + row) * K + kt + lc];
      Bs[lc + 0][row] = bv.x; Bs[lc + 1][row] = bv.y;
      Bs[lc + 2][row] = bv.z; Bs[lc + 3][row] = bv.w;
    }
    __syncthreads();
    #pragma unroll
    for (int kk = 0; kk < 16; ++kk) {
      const float4 a0 = *(const float4*)&As[kk][rowg];
      const float4 a1 = *(const float4*)&As[kk][rowg + 4];
      const float4 b0 = *(const float4*)&Bs[kk][colg];
      const float4 b1 = *(const float4*)&Bs[kk][colg + 4];
      const float ar[8] = {a0.x, a0.y, a0.z, a0.w, a1.x, a1.y, a1.z, a1.w};
      const float br[8] = {b0.x, b0.y, b0.z, b0.w, b1.x, b1.y, b1.z, b1.w};
      #pragma unroll
      for (int i = 0; i < 8; ++i)
        #pragma unroll
        for (int j = 0; j < 8; ++j)
          acc[i][j] += ar[i] * br[j];
    }
    __syncthreads();
  }

  #pragma unroll
  for (int i = 0; i < 8; ++i) {
    const size_t gm = (size_t)(bm + rowg + i);
    #pragma unroll
    for (int j = 0; j < 8; j += 4) {
      float4 o;
      o.x = acc[i][j + 0] + bias[bn + colg + j + 0];
      o.y = acc[i][j + 1] + bias[bn + colg + j + 1];
      o.z = acc[i][j + 2] + bias[bn + colg + j + 2];
      o.w = acc[i][j + 3] + bias[bn + colg + j + 3];
      *(float4*)&C[gm * 1024 + bn + colg + j] = o;
    }
  }
}

// ---------------------------------------------------------------------------
// Spike + bitpack: one wave per (tensor, b, t, h): lane d reads q[b,t,h*64+d],
// __ballot(q>1) packs the 64 spikes into one uint64 -> bits[(b*H+h)*T + t].
// ---------------------------------------------------------------------------
__global__ __launch_bounds__(256) void spike_pack(
    const float* __restrict__ qbuf, const float* __restrict__ kbuf,
    u64* __restrict__ qbits, u64* __restrict__ kbits)
{
  const int gtid  = blockIdx.x * 256 + threadIdx.x;
  const int wid   = gtid >> 6;
  const int lane  = gtid & 63;
  const int which = wid >> 16;      // 0: q, 1: k  (B*T*H = 65536 waves each)
  const int idx   = wid & 65535;
  const int m = idx >> 4;           // b*T + t
  const int h = idx & 15;
  const float* src = (which ? kbuf : qbuf) + (size_t)m * C_DIM + h * 64 + lane;
  const u64 mask = __ballot(*src > 1.0f);
  if (lane == 0) {
    const int b = m >> 11;
    const int t = m & 2047;
    (which ? kbits : qbits)[((size_t)(b * H_NUM + h)) * T_LEN + t] = mask;
  }
}

// ---------------------------------------------------------------------------
// Attention: per block = one (b,h) x 64-query tile. Key tiles of 64:
//  phase1 stage v[64][64] + kbits[64] in LDS;
//  phase2 w[q][k] = exp(popc(qb&kb)*0.125) (no max-subtraction needed: s<=8);
//  phase3 PV with 4q x 4d register tile per thread (16 FMA per key per thread).
// Z accumulated per (q, k-slice) thread across tiles, reduced at the end.
// ---------------------------------------------------------------------------
__global__ __launch_bounds__(256) void attn_kernel(
    const u64* __restrict__ qbits, const u64* __restrict__ kbits,
    const float* __restrict__ vbuf, float* __restrict__ attnout)
{
  __shared__ float vt[64][64];
  __shared__ float wt[64][65];    // pad -> <=2-way bank aliasing (free)
  __shared__ u64   kbt[64];
  __shared__ float zred[256];

  const int tid = threadIdx.x;
  const int bid = blockIdx.x;     // grid = 32 bh * 32 qtiles = 1024
  const int qt  = bid & 31;
  const int bh  = bid >> 5;       // b*16 + h
  const int b   = bh >> 4;
  const int h   = bh & 15;

  // w-phase mapping: thread = (query qw, k-slice of 16)
  const int qw  = tid >> 2;
  const int ks0 = (tid & 3) << 4;
  const u64 myqb = qbits[(size_t)bh * T_LEN + qt * 64 + qw];
  float zacc = 0.f;

  // PV mapping: 16 query-groups x 16 dim-groups
  const int qg = tid >> 4;
  const int dg = tid & 15;
  float acc[4][4];
  #pragma unroll
  for (int i = 0; i < 4; ++i)
    #pragma unroll
    for (int j = 0; j < 4; ++j) acc[i][j] = 0.f;

  const float* vbase = vbuf + (size_t)(b * T_LEN) * C_DIM + h * 64;

  for (int kt = 0; kt < T_LEN; kt += 64) {
    // stage v tile: 1024 float4, 4 per thread, coalesced
    #pragma unroll
    for (int j = 0; j < 4; ++j) {
      const int slot = tid + j * 256;
      const int r  = slot >> 4;
      const int c4 = (slot & 15) << 2;
      *(float4*)&vt[r][c4] = *(const float4*)&vbase[(size_t)(kt + r) * C_DIM + c4];
    }
    if (tid < 64) kbt[tid] = kbits[(size_t)bh * T_LEN + kt + tid];
    __syncthreads();

    // scores -> weights
    #pragma unroll
    for (int i = 0; i < 16; ++i) {
      const int kk = ks0 + i;
      const int mm = __popcll(myqb & kbt[kk]);
      const float w = __expf((float)mm * 0.125f);
      wt[qw][kk] = w;
      zacc += w;
    }
    __syncthreads();

    // PV accumulate
    #pragma unroll 8
    for (int kk = 0; kk < 64; ++kk) {
      const float w0 = wt[qg * 4 + 0][kk];
      const float w1 = wt[qg * 4 + 1][kk];
      const float w2 = wt[qg * 4 + 2][kk];
      const float w3 = wt[qg * 4 + 3][kk];
      const float4 v4 = *(const float4*)&vt[kk][dg << 2];
      acc[0][0] += w0 * v4.x; acc[0][1] += w0 * v4.y; acc[0][2] += w0 * v4.z; acc[0][3] += w0 * v4.w;
      acc[1][0] += w1 * v4.x; acc[1][1] += w1 * v4.y; acc[1][2] += w1 * v4.z; acc[1][3] += w1 * v4.w;
      acc[2][0] += w2 * v4.x; acc[2][1] += w2 * v4.y; acc[2][2] += w2 * v4.z; acc[2][3] += w2 * v4.w;
      acc[3][0] += w3 * v4.x; acc[3][1] += w3 * v4.y; acc[3][2] += w3 * v4.z; acc[3][3] += w3 * v4.w;
    }
    __syncthreads();
  }

  zred[tid] = zacc;
  __syncthreads();

  #pragma unroll
  for (int i = 0; i < 4; ++i) {
    const int q = qg * 4 + i;
    const float Z = zred[q * 4 + 0] + zred[q * 4 + 1] + zred[q * 4 + 2] + zred[q * 4 + 3];
    const float inv = 1.0f / Z;
    const size_t gm = (size_t)(b * T_LEN + qt * 64 + q);
    float4 o;
    o.x = acc[i][0] * inv; o.y = acc[i][1] * inv;
    o.z = acc[i][2] * inv; o.w = acc[i][3] * inv;
    *(float4*)&attnout[gm * C_DIM + h * 64 + (dg << 2)] = o;
  }
}

// ---------------------------------------------------------------------------
extern "C" void kernel_launch(void* const* d_in, const int* in_sizes, int n_in,
                              void* d_out, int out_size, void* d_ws, size_t ws_size,
                              hipStream_t stream) {
  const float* x  = (const float*)d_in[0];
  const float* Wq = (const float*)d_in[1];
  const float* bq = (const float*)d_in[2];
  const float* Wk = (const float*)d_in[3];
  const float* bk = (const float*)d_in[4];
  const float* Wv = (const float*)d_in[5];
  const float* bv = (const float*)d_in[6];
  const float* Wo = (const float*)d_in[7];
  const float* bo = (const float*)d_in[8];
  float* out = (float*)d_out;

  // Workspace layout (needs ~49.3 MB):
  //   qbuf [4096][1024] f32 | kbuf | vbuf | qbits 65536 u64 | kbits 65536 u64
  // attention output reuses qbuf (q fp32 values are dead after spike_pack).
  float* qbuf = (float*)d_ws;
  float* kbuf = qbuf + (size_t)M_ROWS * C_DIM;
  float* vbuf = kbuf + (size_t)M_ROWS * C_DIM;
  u64* qbits  = (u64*)(vbuf + (size_t)M_ROWS * C_DIM);
  u64* kbits  = qbits + (size_t)M_ROWS * H_NUM / 1;  // 65536? no: B*T*H = 65536
  // (B*T*H = 2*2048*16 = 65536 u64 entries per tensor)

  // 1) fused QKV projection: N = 3072 across {Wq,Wk,Wv}
  dim3 g1(M_ROWS / 128, 3072 / 128);
  gemm128<<<g1, 256, 0, stream>>>(x, Wq, Wk, Wv, bq, bk, bv,
                                  qbuf, kbuf, vbuf, C_DIM);

  // 2) spike + bitpack q,k -> uint64 per (b,h,t)
  spike_pack<<<(2 * M_ROWS * H_NUM * 64) / 256, 256, 0, stream>>>(
      qbuf, kbuf, qbits, kbits);

  // 3) popcount-attention (writes into qbuf as attnout)
  attn_kernel<<<32 * 32, 256, 0, stream>>>(qbits, kbits, vbuf, qbuf);

  // 4) output projection: out = attnout @ Wo^T + bo
  dim3 g2(M_ROWS / 128, 1024 / 128);
  gemm128<<<g2, 256, 0, stream>>>(qbuf, Wo, Wo, Wo, bo, bo, bo,
                                  out, out, out, C_DIM);
}

// Round 2
// 401.167 us; speedup vs baseline: 1.7736x; 1.7736x over previous
//
#include <hip/hip_runtime.h>
#include <cstdint>

typedef unsigned long long u64;
typedef unsigned short u16;
typedef __attribute__((ext_vector_type(8))) u16 u16x8;
typedef __attribute__((ext_vector_type(4))) u16 u16x4;
typedef __attribute__((ext_vector_type(4))) float f32x4;

#define T_LEN 2048
#define C_DIM 1024
#define H_NUM 16
#define M_ROWS 4096  // B*T
#define MB (1024ull * 1024ull)

// bf16 helpers (manual RNE, finite inputs only — matches hardware cvt)
__device__ __forceinline__ u16 f2bf(float f) {
  unsigned u = __builtin_bit_cast(unsigned, f);
  return (u16)((u + 0x7FFFu + ((u >> 16) & 1u)) >> 16);
}
__device__ __forceinline__ float bf2f(u16 u) {
  return __builtin_bit_cast(float, ((unsigned)u) << 16);
}

// ---------------------------------------------------------------------------
// Split fp32 -> (hi, lo) bf16 pair: hi = bf16(x), lo = bf16(x - hi).
// ---------------------------------------------------------------------------
__global__ __launch_bounds__(256) void split_bf16(
    const float* __restrict__ src, u16* __restrict__ hi, u16* __restrict__ lo,
    int n4)
{
  const int i = blockIdx.x * 256 + threadIdx.x;
  if (i >= n4) return;
  const float4 v = ((const float4*)src)[i];
  u16x4 h, l;
  float x;
  x = v.x; h[0] = f2bf(x); l[0] = f2bf(x - bf2f(h[0]));
  x = v.y; h[1] = f2bf(x); l[1] = f2bf(x - bf2f(h[1]));
  x = v.z; h[2] = f2bf(x); l[2] = f2bf(x - bf2f(h[2]));
  x = v.w; h[3] = f2bf(x); l[3] = f2bf(x - bf2f(h[3]));
  ((u16x4*)hi)[i] = h;
  ((u16x4*)lo)[i] = l;
}

// ---------------------------------------------------------------------------
// fp32 GEMM (q,k only — spike threshold needs fp32-grade accuracy).
// 128x128 tile, 8x8 micro-tile. Col groups split 4+4 (stride-4 floats) so the
// Bs ds_read_b128 covers all 8 bank-quads uniformly (was 4-of-8 -> 2x LDS cyc).
// ---------------------------------------------------------------------------
__global__ __launch_bounds__(256) void gemm128(
    const float* __restrict__ A,
    const float* B0, const float* B1, const float* B2,
    const float* bias0, const float* bias1, const float* bias2,
    float* C0, float* C1, float* C2, int K)
{
  __shared__ float As[16][132];
  __shared__ float Bs[16][132];
  const int tid = threadIdx.x;
  const int bm  = blockIdx.x * 128;
  const int bng = blockIdx.y * 128;
  const int sel = bng >> 10;
  const int bn  = bng & 1023;
  const float* Bt   = (sel == 0) ? B0 : (sel == 1) ? B1 : B2;
  const float* bias = (sel == 0) ? bias0 : (sel == 1) ? bias1 : bias2;
  float* C          = (sel == 0) ? C0 : (sel == 1) ? C1 : C2;

  const int rowg = (tid >> 4) << 3;   // 8 contiguous rows
  const int colg = (tid & 15) << 2;   // 4 cols at colg, 4 at colg+64
  const int lrow = tid >> 2;
  const int lc   = (tid & 3) << 2;

  float acc[8][8];
  #pragma unroll
  for (int i = 0; i < 8; ++i)
    #pragma unroll
    for (int j = 0; j < 8; ++j) acc[i][j] = 0.f;

  for (int kt = 0; kt < K; kt += 16) {
    #pragma unroll
    for (int jj = 0; jj < 2; ++jj) {
      const int row = lrow + jj * 64;
      const float4 av = *(const float4*)&A[(size_t)(bm + row) * K + kt + lc];
      As[lc + 0][row] = av.x; As[lc + 1][row] = av.y;
      As[lc + 2][row] = av.z; As[lc + 3][row] = av.w;
      const float4 bv = *(const float4*)&Bt[(size_t)(bn + row) * K + kt + lc];
      Bs[lc + 0][row] = bv.x; Bs[lc + 1][row] = bv.y;
      Bs[lc + 2][row] = bv.z; Bs[lc + 3][row] = bv.w;
    }
    __syncthreads();
    #pragma unroll
    for (int kk = 0; kk < 16; ++kk) {
      const float4 a0 = *(const float4*)&As[kk][rowg];
      const float4 a1 = *(const float4*)&As[kk][rowg + 4];
      const float4 b0 = *(const float4*)&Bs[kk][colg];
      const float4 b1 = *(const float4*)&Bs[kk][colg + 64];
      const float ar[8] = {a0.x, a0.y, a0.z, a0.w, a1.x, a1.y, a1.z, a1.w};
      const float br[8] = {b0.x, b0.y, b0.z, b0.w, b1.x, b1.y, b1.z, b1.w};
      #pragma unroll
      for (int i = 0; i < 8; ++i)
        #pragma unroll
        for (int j = 0; j < 8; ++j)
          acc[i][j] += ar[i] * br[j];
    }
    __syncthreads();
  }

  #pragma unroll
  for (int i = 0; i < 8; ++i) {
    const size_t gm = (size_t)(bm + rowg + i);
    float4 o0, o1;
    o0.x = acc[i][0] + bias[bn + colg + 0];
    o0.y = acc[i][1] + bias[bn + colg + 1];
    o0.z = acc[i][2] + bias[bn + colg + 2];
    o0.w = acc[i][3] + bias[bn + colg + 3];
    o1.x = acc[i][4] + bias[bn + 64 + colg + 0];
    o1.y = acc[i][5] + bias[bn + 64 + colg + 1];
    o1.z = acc[i][6] + bias[bn + 64 + colg + 2];
    o1.w = acc[i][7] + bias[bn + 64 + colg + 3];
    *(float4*)&C[gm * 1024 + bn + colg]      = o0;
    *(float4*)&C[gm * 1024 + bn + 64 + colg] = o1;
  }
}

// ---------------------------------------------------------------------------
// Spike + bitpack (unchanged, verified): one wave per (tensor,b,t,h).
// ---------------------------------------------------------------------------
__global__ __launch_bounds__(256) void spike_pack(
    const float* __restrict__ qbuf, const float* __restrict__ kbuf,
    u64* __restrict__ qbits, u64* __restrict__ kbits)
{
  const int gtid  = blockIdx.x * 256 + threadIdx.x;
  const int wid   = gtid >> 6;
  const int lane  = gtid & 63;
  const int which = wid >> 16;
  const int idx   = wid & 65535;
  const int m = idx >> 4;
  const int h = idx & 15;
  const float* src = (which ? kbuf : qbuf) + (size_t)m * C_DIM + h * 64 + lane;
  const u64 mask = __ballot(*src > 1.0f);
  if (lane == 0) {
    const int b = m >> 11;
    const int t = m & 2047;
    (which ? kbits : qbits)[((size_t)(b * H_NUM + h)) * T_LEN + t] = mask;
  }
}

// ---------------------------------------------------------------------------
// 3-pass split-bf16 MFMA GEMM: D = A*Bt^T + bias where A = Ah+Al, Bt = Bh+Bl
// (lo*lo dropped, ~2^-16 rel). BM=128, BN=64, BK=32, 256 thr = 4 waves, each
// wave a 64x32 quadrant (4x2 frags of 16x16x32). Fragment-major LDS layout
// [g][row][8] so frag reads are contiguous ds_read_b128, uniform bank quads.
// Reg-staged global->LDS with next-tile prefetch issued under compute.
// MODE 0: fp32 out [M][1024] + bias.
// MODE 1: bf16 out pre-transposed vT[bh=32][d=64][t=2048] + bias.
// ---------------------------------------------------------------------------
template <int MODE>
__global__ __launch_bounds__(256) void mfma_gemm(
    const u16* __restrict__ Ah, const u16* __restrict__ Al,
    const u16* __restrict__ Bh, const u16* __restrict__ Bl,
    const float* __restrict__ bias, void* __restrict__ outp)
{
  __shared__ u16 Ahs[4][128][8];
  __shared__ u16 Als[4][128][8];
  __shared__ u16 Bhs[4][64][8];
  __shared__ u16 Bls[4][64][8];

  const int tid  = threadIdx.x;
  const int lane = tid & 63;
  const int w    = tid >> 6;
  const int wr   = w & 1;    // M half (64 rows)
  const int wc   = w >> 1;   // N half (32 cols)
  const int bm   = blockIdx.x * 128;
  const int bn   = blockIdx.y * 64;

  f32x4 acc[4][2];
  #pragma unroll
  for (int mf = 0; mf < 4; ++mf)
    #pragma unroll
    for (int nf = 0; nf < 2; ++nf) acc[mf][nf] = (f32x4){0.f, 0.f, 0.f, 0.f};

  const int srow = tid >> 2;   // 0..63
  const int sg   = tid & 3;    // k-group

  u16x8 r0, r1, r2, r3, r4, r5;
  const size_t a0base = (size_t)(bm + srow) * 1024 + sg * 8;
  const size_t b0base = (size_t)(bn + srow) * 1024 + sg * 8;

#define MG_LOAD(KT)                                   \
  {                                                   \
    r0 = *(const u16x8*)&Ah[a0base + (KT)];           \
    r1 = *(const u16x8*)&Ah[a0base + 64 * 1024 + (KT)]; \
    r2 = *(const u16x8*)&Al[a0base + (KT)];           \
    r3 = *(const u16x8*)&Al[a0base + 64 * 1024 + (KT)]; \
    r4 = *(const u16x8*)&Bh[b0base + (KT)];           \
    r5 = *(const u16x8*)&Bl[b0base + (KT)];           \
  }

  MG_LOAD(0);
  const int fr = lane & 15;
  const int fg = lane >> 4;

  for (int kt = 0; kt < 1024; kt += 32) {
    *(u16x8*)&Ahs[sg][srow][0]      = r0;
    *(u16x8*)&Ahs[sg][64 + srow][0] = r1;
    *(u16x8*)&Als[sg][srow][0]      = r2;
    *(u16x8*)&Als[sg][64 + srow][0] = r3;
    *(u16x8*)&Bhs[sg][srow][0]      = r4;
    *(u16x8*)&Bls[sg][srow][0]      = r5;
    __syncthreads();
    if (kt + 32 < 1024) MG_LOAD(kt + 32);

    u16x8 a_h[4], a_l[4], b_h[2], b_l[2];
    #pragma unroll
    for (int mf = 0; mf < 4; ++mf) {
      const int row = wr * 64 + mf * 16 + fr;
      a_h[mf] = *(const u16x8*)&Ahs[fg][row][0];
      a_l[mf] = *(const u16x8*)&Als[fg][row][0];
    }
    #pragma unroll
    for (int nf = 0; nf < 2; ++nf) {
      const int col = wc * 32 + nf * 16 + fr;
      b_h[nf] = *(const u16x8*)&Bhs[fg][col][0];
      b_l[nf] = *(const u16x8*)&Bls[fg][col][0];
    }
    #pragma unroll
    for (int mf = 0; mf < 4; ++mf)
      #pragma unroll
      for (int nf = 0; nf < 2; ++nf) {
        acc[mf][nf] = __builtin_amdgcn_mfma_f32_16x16x32_bf16(a_h[mf], b_h[nf], acc[mf][nf], 0, 0, 0);
        acc[mf][nf] = __builtin_amdgcn_mfma_f32_16x16x32_bf16(a_h[mf], b_l[nf], acc[mf][nf], 0, 0, 0);
        acc[mf][nf] = __builtin_amdgcn_mfma_f32_16x16x32_bf16(a_l[mf], b_h[nf], acc[mf][nf], 0, 0, 0);
      }
    __syncthreads();
  }
#undef MG_LOAD

  // Epilogue. C/D frag layout: col = lane&15, row = (lane>>4)*4 + j.
  #pragma unroll
  for (int mf = 0; mf < 4; ++mf) {
    const int row0 = bm + wr * 64 + mf * 16 + fg * 4;
    #pragma unroll
    for (int nf = 0; nf < 2; ++nf) {
      const int col = bn + wc * 32 + nf * 16 + fr;
      const float bb = bias[col];
      if (MODE == 0) {
        float* out = (float*)outp;
        #pragma unroll
        for (int j = 0; j < 4; ++j)
          out[(size_t)(row0 + j) * 1024 + col] = acc[mf][nf][j] + bb;
      } else {
        // vT[bh][d][t]: col -> (h = col>>6, d = col&63); row -> (b, t)
        u16* out = (u16*)outp;
        const int bb_ = row0 >> 11, t0 = row0 & 2047;
        const int hh = col >> 6, dd = col & 63;
        u16x4 o;
        o[0] = f2bf(acc[mf][nf][0] + bb);
        o[1] = f2bf(acc[mf][nf][1] + bb);
        o[2] = f2bf(acc[mf][nf][2] + bb);
        o[3] = f2bf(acc[mf][nf][3] + bb);
        *(u16x4*)&out[(((size_t)(bb_ * 16 + hh)) * 64 + dd) * 2048 + t0] = o;
      }
    }
  }
}

// ---------------------------------------------------------------------------
// MFMA attention: per block = (bh, 64-query tile), 4 waves. Per 64-key tile:
//   stage vtb[d][k] (bf16, from pre-transposed vT) + kbt;
//   weights w = exp(popc/8) -> bf16 wtb[q][k] (Z uses same bf16 value so the
//   output is an exact weighted mean — truncation cancels to 1st order);
//   PV: wave w does rows w*16..+16 x all 64 dims, K=64 (8 MFMAs).
// Epilogue divides by Z and writes hi/lo bf16 for the 3-pass out-proj.
// ---------------------------------------------------------------------------
__global__ __launch_bounds__(256) void attn_mfma(
    const u64* __restrict__ qbits, const u64* __restrict__ kbits,
    const u16* __restrict__ vT, u16* __restrict__ oh, u16* __restrict__ ol)
{
  __shared__ u16 wtb[64][72];
  __shared__ u16 vtb[64][72];
  __shared__ u64 kbt[64];
  __shared__ float zred[256];
  __shared__ float zfin[64];

  const int tid = threadIdx.x, lane = tid & 63, w = tid >> 6;
  const int bid = blockIdx.x;
  const int qt = bid & 31, bh = bid >> 5, b = bh >> 4, h = bh & 15;

  const int qw = tid >> 2, ks0 = (tid & 3) << 4;
  const u64 myqb = qbits[(size_t)bh * T_LEN + qt * 64 + qw];
  float zacc = 0.f;

  f32x4 acc[4];
  #pragma unroll
  for (int nf = 0; nf < 4; ++nf) acc[nf] = (f32x4){0.f, 0.f, 0.f, 0.f};

  const u16* vbase = vT + (size_t)bh * 64 * T_LEN;
  const int sd = tid >> 2, sk = (tid & 3) << 3;
  const int fr = lane & 15, fg = lane >> 4;

  for (int kt = 0; kt < T_LEN; kt += 64) {
    *(u16x8*)&vtb[sd][sk]      = *(const u16x8*)&vbase[(size_t)sd * T_LEN + kt + sk];
    *(u16x8*)&vtb[sd][sk + 32] = *(const u16x8*)&vbase[(size_t)sd * T_LEN + kt + sk + 32];
    if (tid < 64) kbt[tid] = kbits[(size_t)bh * T_LEN + kt + tid];
    __syncthreads();

    #pragma unroll
    for (int i = 0; i < 16; ++i) {
      const int kk = ks0 + i;
      const int mm = __popcll(myqb & kbt[kk]);
      const u16 wb = f2bf(__expf((float)mm * 0.125f));
      wtb[qw][kk] = wb;
      zacc += bf2f(wb);
    }
    __syncthreads();

    #pragma unroll
    for (int ks = 0; ks < 2; ++ks) {
      const u16x8 af = *(const u16x8*)&wtb[w * 16 + fr][ks * 32 + fg * 8];
      #pragma unroll
      for (int nf = 0; nf < 4; ++nf) {
        const u16x8 bfv = *(const u16x8*)&vtb[nf * 16 + fr][ks * 32 + fg * 8];
        acc[nf] = __builtin_amdgcn_mfma_f32_16x16x32_bf16(af, bfv, acc[nf], 0, 0, 0);
      }
    }
    __syncthreads();
  }

  zred[tid] = zacc;
  __syncthreads();
  if (tid < 64)
    zfin[tid] = zred[tid * 4] + zred[tid * 4 + 1] + zred[tid * 4 + 2] + zred[tid * 4 + 3];
  __syncthreads();

  #pragma unroll
  for (int nf = 0; nf < 4; ++nf) {
    const int col = h * 64 + nf * 16 + fr;
    #pragma unroll
    for (int j = 0; j < 4; ++j) {
      const int qrow = w * 16 + fg * 4 + j;
      const float o = acc[nf][j] / zfin[qrow];
      const size_t gq = (size_t)b * T_LEN + qt * 64 + qrow;
      const u16 hb = f2bf(o);
      oh[gq * 1024 + col] = hb;
      ol[gq * 1024 + col] = f2bf(o - bf2f(hb));
    }
  }
}

// ---------------------------------------------------------------------------
extern "C" void kernel_launch(void* const* d_in, const int* in_sizes, int n_in,
                              void* d_out, int out_size, void* d_ws, size_t ws_size,
                              hipStream_t stream) {
  const float* x  = (const float*)d_in[0];
  const float* Wq = (const float*)d_in[1];
  const float* bq = (const float*)d_in[2];
  const float* Wk = (const float*)d_in[3];
  const float* bk = (const float*)d_in[4];
  const float* Wv = (const float*)d_in[5];
  const float* bv = (const float*)d_in[6];
  const float* Wo = (const float*)d_in[7];
  const float* bo = (const float*)d_in[8];
  float* out = (float*)d_out;

  // Workspace (49 MB). q lives in d_out (dead after spike_pack; out-proj
  // rewrites d_out last). oh/ol overlay kbuf (dead after spike_pack).
  char* ws = (char*)d_ws;
  float* kbuf = (float*)ws;                    // [0,16MB)
  u16* oh     = (u16*)ws;                      // [0,8MB)   (after pack)
  u16* ol     = (u16*)(ws + 8 * MB);           // [8,16MB)  (after pack)
  u16* xh     = (u16*)(ws + 16 * MB);
  u16* xl     = (u16*)(ws + 24 * MB);
  u16* vT     = (u16*)(ws + 32 * MB);          // [32][64][2048] bf16
  u16* Wvh    = (u16*)(ws + 40 * MB);
  u16* Wvl    = (u16*)(ws + 42 * MB);
  u16* Woh    = (u16*)(ws + 44 * MB);
  u16* Wol    = (u16*)(ws + 46 * MB);
  u64* qbits  = (u64*)(ws + 48 * MB);
  u64* kbits  = qbits + 65536;
  float* qbuf = out;                           // q scratch in d_out

  // 1) hi/lo bf16 splits for the MFMA operands
  split_bf16<<<(M_ROWS * C_DIM / 4 + 255) / 256, 256, 0, stream>>>(x, xh, xl, M_ROWS * C_DIM / 4);
  split_bf16<<<(C_DIM * C_DIM / 4 + 255) / 256, 256, 0, stream>>>(Wv, Wvh, Wvl, C_DIM * C_DIM / 4);
  split_bf16<<<(C_DIM * C_DIM / 4 + 255) / 256, 256, 0, stream>>>(Wo, Woh, Wol, C_DIM * C_DIM / 4);

  // 2) q,k projection in fp32 (spike accuracy), N = 2048
  dim3 g1(M_ROWS / 128, 2048 / 128);
  gemm128<<<g1, 256, 0, stream>>>(x, Wq, Wk, Wq, bq, bk, bq,
                                  qbuf, kbuf, qbuf, C_DIM);

  // 3) spike + bitpack
  spike_pack<<<(2 * M_ROWS * H_NUM * 64) / 256, 256, 0, stream>>>(
      qbuf, kbuf, qbits, kbits);

  // 4) v projection, 3-pass MFMA, writes pre-transposed bf16 vT
  dim3 g2(M_ROWS / 128, 1024 / 64);
  mfma_gemm<1><<<g2, 256, 0, stream>>>(xh, xl, Wvh, Wvl, bv, (void*)vT);

  // 5) popcount-attention with MFMA PV -> hi/lo bf16 attn output
  attn_mfma<<<32 * 32, 256, 0, stream>>>(qbits, kbits, vT, oh, ol);

  // 6) out projection, 3-pass MFMA, fp32 out + bias
  mfma_gemm<0><<<g2, 256, 0, stream>>>(oh, ol, Woh, Wol, bo, (void*)out);
}

// Round 3
// 246.529 us; speedup vs baseline: 2.8861x; 1.6273x over previous
//
#include <hip/hip_runtime.h>
#include <cstdint>

typedef unsigned long long u64;
typedef unsigned int u32;
typedef unsigned short u16;
typedef __attribute__((ext_vector_type(8))) u16 u16x8;
typedef __attribute__((ext_vector_type(4))) u16 u16x4;
typedef __attribute__((ext_vector_type(4))) float f32x4;

#define T_LEN 2048
#define C_DIM 1024
#define H_NUM 16
#define M_ROWS 4096  // B*T
#define MB (1024ull * 1024ull)
#define TAU 2e-4f
#define FCAP 65536u

// bf16 helpers (manual RNE, finite inputs only)
__device__ __forceinline__ u16 f2bf(float f) {
  unsigned u = __builtin_bit_cast(unsigned, f);
  return (u16)((u + 0x7FFFu + ((u >> 16) & 1u)) >> 16);
}
__device__ __forceinline__ float bf2f(u16 u) {
  return __builtin_bit_cast(float, ((unsigned)u) << 16);
}

// ---------------------------------------------------------------------------
// Split fp32 -> (hi,lo) bf16 for x, Wq, Wk, Wv, Wo in one launch.
// Flat float4 index: x 1048576 | Wq 262144 | Wk | Wv | Wo. Grid 8192x256.
// Thread 0 zeroes the flag counter.
// ---------------------------------------------------------------------------
__global__ __launch_bounds__(256) void split_all(
    const float* __restrict__ x,  const float* __restrict__ Wq,
    const float* __restrict__ Wk, const float* __restrict__ Wv,
    const float* __restrict__ Wo,
    u16* xh, u16* xl, u16* wqh, u16* wql, u16* wkh, u16* wkl,
    u16* wvh, u16* wvl, u16* woh, u16* wol, u32* flagcnt)
{
  const int i = blockIdx.x * 256 + threadIdx.x;
  if (i == 0) *flagcnt = 0;
  const float* src; u16 *hi, *lo; int off;
  if      (i < 1048576) { src = x;  hi = xh;  lo = xl;  off = i; }
  else if (i < 1310720) { src = Wq; hi = wqh; lo = wql; off = i - 1048576; }
  else if (i < 1572864) { src = Wk; hi = wkh; lo = wkl; off = i - 1310720; }
  else if (i < 1835008) { src = Wv; hi = wvh; lo = wvl; off = i - 1572864; }
  else                  { src = Wo; hi = woh; lo = wol; off = i - 1835008; }
  const float4 v = ((const float4*)src)[off];
  u16x4 h, l;
  float t;
  t = v.x; h[0] = f2bf(t); l[0] = f2bf(t - bf2f(h[0]));
  t = v.y; h[1] = f2bf(t); l[1] = f2bf(t - bf2f(h[1]));
  t = v.z; h[2] = f2bf(t); l[2] = f2bf(t - bf2f(h[2]));
  t = v.w; h[3] = f2bf(t); l[3] = f2bf(t - bf2f(h[3]));
  ((u16x4*)hi)[off] = h;
  ((u16x4*)lo)[off] = l;
}

// ---------------------------------------------------------------------------
// Fused QKV 3-pass split-bf16 MFMA GEMM over N=3072 (sel 0:q, 1:k, 2:v).
// BM=128, BN=64, BK=32, 4 waves, wave = 64x32 quadrant of 16x16x32 frags.
// sel 0/1 epilogue: spike = (acc+bias) > 1 -> ballot -> packed u32 per
//   (m, head, half); near-threshold entries appended to flag list.
// sel 2 epilogue: bf16 out pre-transposed vT[bh][d][t] + bias.
// pbits layout: [which][m][head][half] u32.
// ---------------------------------------------------------------------------
__global__ __launch_bounds__(256) void mfma_qkv(
    const u16* __restrict__ Ah, const u16* __restrict__ Al,
    const u16* __restrict__ Bqh, const u16* __restrict__ Bql,
    const u16* __restrict__ Bkh, const u16* __restrict__ Bkl,
    const u16* __restrict__ Bvh, const u16* __restrict__ Bvl,
    const float* __restrict__ bq, const float* __restrict__ bk,
    const float* __restrict__ bv,
    u32* __restrict__ pbits, u32* __restrict__ flagcnt,
    u32* __restrict__ flaglist, u16* __restrict__ vT)
{
  __shared__ u16 Ahs[4][128][8];
  __shared__ u16 Als[4][128][8];
  __shared__ u16 Bhs[4][64][8];
  __shared__ u16 Bls[4][64][8];

  const int tid  = threadIdx.x;
  const int lane = tid & 63;
  const int w    = tid >> 6;
  const int wr   = w & 1;
  const int wc   = w >> 1;
  const int bm   = blockIdx.x * 128;
  const int bng  = blockIdx.y * 64;
  const int sel  = bng >> 10;
  const int bnl  = bng & 1023;

  const u16* Bh   = (sel == 0) ? Bqh : (sel == 1) ? Bkh : Bvh;
  const u16* Bl   = (sel == 0) ? Bql : (sel == 1) ? Bkl : Bvl;
  const float* bias = (sel == 0) ? bq : (sel == 1) ? bk : bv;

  f32x4 acc[4][2];
  #pragma unroll
  for (int mf = 0; mf < 4; ++mf)
    #pragma unroll
    for (int nf = 0; nf < 2; ++nf) acc[mf][nf] = (f32x4){0.f, 0.f, 0.f, 0.f};

  const int srow = tid >> 2;
  const int sg   = tid & 3;

  u16x8 r0, r1, r2, r3, r4, r5;
  const size_t a0base = (size_t)(bm + srow) * 1024 + sg * 8;
  const size_t b0base = (size_t)(bnl + srow) * 1024 + sg * 8;

#define MG_LOAD(KT)                                     \
  {                                                     \
    r0 = *(const u16x8*)&Ah[a0base + (KT)];             \
    r1 = *(const u16x8*)&Ah[a0base + 64 * 1024 + (KT)]; \
    r2 = *(const u16x8*)&Al[a0base + (KT)];             \
    r3 = *(const u16x8*)&Al[a0base + 64 * 1024 + (KT)]; \
    r4 = *(const u16x8*)&Bh[b0base + (KT)];             \
    r5 = *(const u16x8*)&Bl[b0base + (KT)];             \
  }

  MG_LOAD(0);
  const int fr = lane & 15;
  const int fg = lane >> 4;

  for (int kt = 0; kt < 1024; kt += 32) {
    *(u16x8*)&Ahs[sg][srow][0]      = r0;
    *(u16x8*)&Ahs[sg][64 + srow][0] = r1;
    *(u16x8*)&Als[sg][srow][0]      = r2;
    *(u16x8*)&Als[sg][64 + srow][0] = r3;
    *(u16x8*)&Bhs[sg][srow][0]      = r4;
    *(u16x8*)&Bls[sg][srow][0]      = r5;
    __syncthreads();
    if (kt + 32 < 1024) MG_LOAD(kt + 32);

    u16x8 a_h[4], a_l[4], b_h[2], b_l[2];
    #pragma unroll
    for (int mf = 0; mf < 4; ++mf) {
      const int row = wr * 64 + mf * 16 + fr;
      a_h[mf] = *(const u16x8*)&Ahs[fg][row][0];
      a_l[mf] = *(const u16x8*)&Als[fg][row][0];
    }
    #pragma unroll
    for (int nf = 0; nf < 2; ++nf) {
      const int col = wc * 32 + nf * 16 + fr;
      b_h[nf] = *(const u16x8*)&Bhs[fg][col][0];
      b_l[nf] = *(const u16x8*)&Bls[fg][col][0];
    }
    #pragma unroll
    for (int mf = 0; mf < 4; ++mf)
      #pragma unroll
      for (int nf = 0; nf < 2; ++nf) {
        acc[mf][nf] = __builtin_amdgcn_mfma_f32_16x16x32_bf16(a_h[mf], b_h[nf], acc[mf][nf], 0, 0, 0);
        acc[mf][nf] = __builtin_amdgcn_mfma_f32_16x16x32_bf16(a_h[mf], b_l[nf], acc[mf][nf], 0, 0, 0);
        acc[mf][nf] = __builtin_amdgcn_mfma_f32_16x16x32_bf16(a_l[mf], b_h[nf], acc[mf][nf], 0, 0, 0);
      }
    __syncthreads();
  }
#undef MG_LOAD

  if (sel < 2) {
    // spike ballots + flags. C/D frag: col=lane&15 (fr), row=(lane>>4)*4+j.
    const int c0 = bnl + wc * 32 + fr;        // nf = 0
    const int c1 = c0 + 16;                   // nf = 1
    const float bb0 = bias[c0];
    const float bb1 = bias[c1];
    const int head = bnl >> 6;
    #pragma unroll
    for (int mf = 0; mf < 4; ++mf) {
      const int row0 = bm + wr * 64 + mf * 16;
      #pragma unroll
      for (int j = 0; j < 4; ++j) {
        const float v0 = acc[mf][0][j] + bb0;
        const float v1 = acc[mf][1][j] + bb1;
        const u64 b0 = __ballot(v0 > 1.0f);
        const u64 b1 = __ballot(v1 > 1.0f);
        const int m = row0 + fg * 4 + j;
        if (fr == 0) {
          const u32 mask = (u32)((b0 >> (fg * 16)) & 0xFFFFu)
                         | ((u32)((b1 >> (fg * 16)) & 0xFFFFu) << 16);
          pbits[(((size_t)sel * 4096 + m) * 16 + head) * 2 + wc] = mask;
        }
        if (__builtin_fabsf(v0 - 1.0f) < TAU) {
          const u32 s = atomicAdd(flagcnt, 1u);
          if (s < FCAP) flaglist[s] = ((u32)sel << 22) | ((u32)m << 10) | (u32)c0;
        }
        if (__builtin_fabsf(v1 - 1.0f) < TAU) {
          const u32 s = atomicAdd(flagcnt, 1u);
          if (s < FCAP) flaglist[s] = ((u32)sel << 22) | ((u32)m << 10) | (u32)c1;
        }
      }
    }
  } else {
    // vT[bh][d][t] bf16 epilogue
    #pragma unroll
    for (int mf = 0; mf < 4; ++mf) {
      const int row0 = bm + wr * 64 + mf * 16 + fg * 4;
      #pragma unroll
      for (int nf = 0; nf < 2; ++nf) {
        const int col = bnl + wc * 32 + nf * 16 + fr;
        const float bb = bias[col];
        const int bb_ = row0 >> 11, t0 = row0 & 2047;
        const int hh = col >> 6, dd = col & 63;
        u16x4 o;
        o[0] = f2bf(acc[mf][nf][0] + bb);
        o[1] = f2bf(acc[mf][nf][1] + bb);
        o[2] = f2bf(acc[mf][nf][2] + bb);
        o[3] = f2bf(acc[mf][nf][3] + bb);
        *(u16x4*)&vT[(((size_t)(bb_ * 16 + hh)) * 64 + dd) * 2048 + t0] = o;
      }
    }
  }
}

// ---------------------------------------------------------------------------
// Recompute near-threshold q/k entries with an exact fp32 dot; patch spike
// bit via atomicXor if the provisional (MFMA) decision differs. One wave per
// flagged entry, grid-stride. No other wave touches the same bit.
// ---------------------------------------------------------------------------
__global__ __launch_bounds__(256) void fix_bits(
    const float* __restrict__ x,
    const float* __restrict__ Wq, const float* __restrict__ Wk,
    const float* __restrict__ bq, const float* __restrict__ bk,
    u32* __restrict__ pbits,
    const u32* __restrict__ flagcnt, const u32* __restrict__ flaglist)
{
  u32 cnt = *flagcnt;
  if (cnt > FCAP) cnt = FCAP;
  const int lane = threadIdx.x & 63;
  const u32 wid  = (blockIdx.x * 256 + threadIdx.x) >> 6;
  const u32 nw   = gridDim.x * 4;
  for (u32 i = wid; i < cnt; i += nw) {
    const u32 e = flaglist[i];
    const int which = e >> 22;
    const int m = (e >> 10) & 4095;
    const int n = e & 1023;
    const float* W    = which ? Wk : Wq;
    const float* bias = which ? bk : bq;
    float s = 0.f;
    #pragma unroll
    for (int j = 0; j < 16; ++j)
      s += x[(size_t)m * 1024 + lane + j * 64] * W[(size_t)n * 1024 + lane + j * 64];
    #pragma unroll
    for (int off = 32; off > 0; off >>= 1) s += __shfl_xor(s, off);
    const float val = s + bias[n];
    if (lane == 0) {
      const size_t idx = (((size_t)which * 4096 + m) * 16 + (n >> 6)) * 2 + ((n >> 5) & 1);
      const u32 bit = 1u << (n & 31);
      const bool oldb = (pbits[idx] >> (n & 31)) & 1u;
      const bool newb = val > 1.0f;
      if (oldb != newb) atomicXor(&pbits[idx], bit);
    }
  }
}

// ---------------------------------------------------------------------------
// MFMA attention (verified structure): per block = (bh, 64-query tile).
// Reads packed spike bits from pbits; V from pre-transposed bf16 vT.
// Writes hi/lo bf16 attn output for the 3-pass out-proj.
// ---------------------------------------------------------------------------
__global__ __launch_bounds__(256) void attn_mfma(
    const u32* __restrict__ pbits, const u16* __restrict__ vT,
    u16* __restrict__ oh, u16* __restrict__ ol)
{
  __shared__ u16 wtb[64][72];
  __shared__ u16 vtb[64][72];
  __shared__ u64 kbt[64];
  __shared__ float zred[256];
  __shared__ float zfin[64];

  const int tid = threadIdx.x, lane = tid & 63, w = tid >> 6;
  const int bid = blockIdx.x;
  const int qt = bid & 31, bh = bid >> 5, b = bh >> 4, h = bh & 15;

  const int qw = tid >> 2, ks0 = (tid & 3) << 4;
  {
  }
  const int qm = b * T_LEN + qt * 64 + qw;
  const size_t qbase = (((size_t)qm) * 16 + h) * 2;
  const u64 myqb = (u64)pbits[qbase] | ((u64)pbits[qbase + 1] << 32);
  float zacc = 0.f;

  f32x4 acc[4];
  #pragma unroll
  for (int nf = 0; nf < 4; ++nf) acc[nf] = (f32x4){0.f, 0.f, 0.f, 0.f};

  const u16* vbase = vT + (size_t)bh * 64 * T_LEN;
  const int sd = tid >> 2, sk = (tid & 3) << 3;
  const int fr = lane & 15, fg = lane >> 4;

  for (int kt = 0; kt < T_LEN; kt += 64) {
    *(u16x8*)&vtb[sd][sk]      = *(const u16x8*)&vbase[(size_t)sd * T_LEN + kt + sk];
    *(u16x8*)&vtb[sd][sk + 32] = *(const u16x8*)&vbase[(size_t)sd * T_LEN + kt + sk + 32];
    if (tid < 64) {
      const int km = b * T_LEN + kt + tid;
      const size_t kb = (((size_t)(4096 + km)) * 16 + h) * 2;
      kbt[tid] = (u64)pbits[kb] | ((u64)pbits[kb + 1] << 32);
    }
    __syncthreads();

    #pragma unroll
    for (int i = 0; i < 16; ++i) {
      const int kk = ks0 + i;
      const int mm = __popcll(myqb & kbt[kk]);
      const u16 wb = f2bf(__expf((float)mm * 0.125f));
      wtb[qw][kk] = wb;
      zacc += bf2f(wb);
    }
    __syncthreads();

    #pragma unroll
    for (int ks = 0; ks < 2; ++ks) {
      const u16x8 af = *(const u16x8*)&wtb[w * 16 + fr][ks * 32 + fg * 8];
      #pragma unroll
      for (int nf = 0; nf < 4; ++nf) {
        const u16x8 bfv = *(const u16x8*)&vtb[nf * 16 + fr][ks * 32 + fg * 8];
        acc[nf] = __builtin_amdgcn_mfma_f32_16x16x32_bf16(af, bfv, acc[nf], 0, 0, 0);
      }
    }
    __syncthreads();
  }

  zred[tid] = zacc;
  __syncthreads();
  if (tid < 64)
    zfin[tid] = zred[tid * 4] + zred[tid * 4 + 1] + zred[tid * 4 + 2] + zred[tid * 4 + 3];
  __syncthreads();

  #pragma unroll
  for (int nf = 0; nf < 4; ++nf) {
    const int col = h * 64 + nf * 16 + fr;
    #pragma unroll
    for (int j = 0; j < 4; ++j) {
      const int qrow = w * 16 + fg * 4 + j;
      const float o = acc[nf][j] / zfin[qrow];
      const size_t gq = (size_t)b * T_LEN + qt * 64 + qrow;
      const u16 hb = f2bf(o);
      oh[gq * 1024 + col] = hb;
      ol[gq * 1024 + col] = f2bf(o - bf2f(hb));
    }
  }
}

// ---------------------------------------------------------------------------
// Out projection: 3-pass split-bf16 MFMA, fp32 out + bias (verified).
// ---------------------------------------------------------------------------
__global__ __launch_bounds__(256) void mfma_out(
    const u16* __restrict__ Ah, const u16* __restrict__ Al,
    const u16* __restrict__ Bh, const u16* __restrict__ Bl,
    const float* __restrict__ bias, float* __restrict__ out)
{
  __shared__ u16 Ahs[4][128][8];
  __shared__ u16 Als[4][128][8];
  __shared__ u16 Bhs[4][64][8];
  __shared__ u16 Bls[4][64][8];

  const int tid  = threadIdx.x;
  const int lane = tid & 63;
  const int w    = tid >> 6;
  const int wr   = w & 1;
  const int wc   = w >> 1;
  const int bm   = blockIdx.x * 128;
  const int bn   = blockIdx.y * 64;

  f32x4 acc[4][2];
  #pragma unroll
  for (int mf = 0; mf < 4; ++mf)
    #pragma unroll
    for (int nf = 0; nf < 2; ++nf) acc[mf][nf] = (f32x4){0.f, 0.f, 0.f, 0.f};

  const int srow = tid >> 2;
  const int sg   = tid & 3;

  u16x8 r0, r1, r2, r3, r4, r5;
  const size_t a0base = (size_t)(bm + srow) * 1024 + sg * 8;
  const size_t b0base = (size_t)(bn + srow) * 1024 + sg * 8;

#define MG_LOAD(KT)                                     \
  {                                                     \
    r0 = *(const u16x8*)&Ah[a0base + (KT)];             \
    r1 = *(const u16x8*)&Ah[a0base + 64 * 1024 + (KT)]; \
    r2 = *(const u16x8*)&Al[a0base + (KT)];             \
    r3 = *(const u16x8*)&Al[a0base + 64 * 1024 + (KT)]; \
    r4 = *(const u16x8*)&Bh[b0base + (KT)];             \
    r5 = *(const u16x8*)&Bl[b0base + (KT)];             \
  }

  MG_LOAD(0);
  const int fr = lane & 15;
  const int fg = lane >> 4;

  for (int kt = 0; kt < 1024; kt += 32) {
    *(u16x8*)&Ahs[sg][srow][0]      = r0;
    *(u16x8*)&Ahs[sg][64 + srow][0] = r1;
    *(u16x8*)&Als[sg][srow][0]      = r2;
    *(u16x8*)&Als[sg][64 + srow][0] = r3;
    *(u16x8*)&Bhs[sg][srow][0]      = r4;
    *(u16x8*)&Bls[sg][srow][0]      = r5;
    __syncthreads();
    if (kt + 32 < 1024) MG_LOAD(kt + 32);

    u16x8 a_h[4], a_l[4], b_h[2], b_l[2];
    #pragma unroll
    for (int mf = 0; mf < 4; ++mf) {
      const int row = wr * 64 + mf * 16 + fr;
      a_h[mf] = *(const u16x8*)&Ahs[fg][row][0];
      a_l[mf] = *(const u16x8*)&Als[fg][row][0];
    }
    #pragma unroll
    for (int nf = 0; nf < 2; ++nf) {
      const int col = wc * 32 + nf * 16 + fr;
      b_h[nf] = *(const u16x8*)&Bhs[fg][col][0];
      b_l[nf] = *(const u16x8*)&Bls[fg][col][0];
    }
    #pragma unroll
    for (int mf = 0; mf < 4; ++mf)
      #pragma unroll
      for (int nf = 0; nf < 2; ++nf) {
        acc[mf][nf] = __builtin_amdgcn_mfma_f32_16x16x32_bf16(a_h[mf], b_h[nf], acc[mf][nf], 0, 0, 0);
        acc[mf][nf] = __builtin_amdgcn_mfma_f32_16x16x32_bf16(a_h[mf], b_l[nf], acc[mf][nf], 0, 0, 0);
        acc[mf][nf] = __builtin_amdgcn_mfma_f32_16x16x32_bf16(a_l[mf], b_h[nf], acc[mf][nf], 0, 0, 0);
      }
    __syncthreads();
  }
#undef MG_LOAD

  #pragma unroll
  for (int mf = 0; mf < 4; ++mf) {
    const int row0 = bm + wr * 64 + mf * 16 + fg * 4;
    #pragma unroll
    for (int nf = 0; nf < 2; ++nf) {
      const int col = bn + wc * 32 + nf * 16 + fr;
      const float bb = bias[col];
      #pragma unroll
      for (int j = 0; j < 4; ++j)
        out[(size_t)(row0 + j) * 1024 + col] = acc[mf][nf][j] + bb;
    }
  }
}

// ---------------------------------------------------------------------------
extern "C" void kernel_launch(void* const* d_in, const int* in_sizes, int n_in,
                              void* d_out, int out_size, void* d_ws, size_t ws_size,
                              hipStream_t stream) {
  const float* x  = (const float*)d_in[0];
  const float* Wq = (const float*)d_in[1];
  const float* bq = (const float*)d_in[2];
  const float* Wk = (const float*)d_in[3];
  const float* bk = (const float*)d_in[4];
  const float* Wv = (const float*)d_in[5];
  const float* bv = (const float*)d_in[6];
  const float* Wo = (const float*)d_in[7];
  const float* bo = (const float*)d_in[8];
  float* out = (float*)d_out;

  // ws (45.3 MB extent):
  //   [0,8)   oh        [8,16)  ol
  //   [16,24) xh        [24,32) xl
  //   [32,40) vT        [40,42) Woh   [42,44) Wol
  //   [44,45) pbits     [45MB]  flagcnt, +256B flaglist
  char* ws = (char*)d_ws;
  u16* oh   = (u16*)ws;
  u16* ol   = (u16*)(ws + 8 * MB);
  u16* xh   = (u16*)(ws + 16 * MB);
  u16* xl   = (u16*)(ws + 24 * MB);
  u16* vT   = (u16*)(ws + 32 * MB);
  u16* Woh  = (u16*)(ws + 40 * MB);
  u16* Wol  = (u16*)(ws + 42 * MB);
  u32* pbits = (u32*)(ws + 44 * MB);
  u32* flagcnt  = (u32*)(ws + 45 * MB);
  u32* flaglist = (u32*)(ws + 45 * MB + 256);

  // d_out doubles as scratch for q/k/v weight splits (dead before out-proj).
  char* dob = (char*)d_out;
  u16* Wqh = (u16*)dob;
  u16* Wql = (u16*)(dob + 2 * MB);
  u16* Wkh = (u16*)(dob + 4 * MB);
  u16* Wkl = (u16*)(dob + 6 * MB);
  u16* Wvh = (u16*)(dob + 8 * MB);
  u16* Wvl = (u16*)(dob + 10 * MB);

  // 1) all hi/lo splits + zero flag counter
  split_all<<<8192, 256, 0, stream>>>(x, Wq, Wk, Wv, Wo,
                                      xh, xl, Wqh, Wql, Wkh, Wkl,
                                      Wvh, Wvl, Woh, Wol, flagcnt);

  // 2) fused QKV MFMA: q/k -> spike bitmasks (+flags), v -> vT bf16
  dim3 g1(M_ROWS / 128, 3072 / 64);
  mfma_qkv<<<g1, 256, 0, stream>>>(xh, xl, Wqh, Wql, Wkh, Wkl, Wvh, Wvl,
                                   bq, bk, bv, pbits, flagcnt, flaglist, vT);

  // 3) recompute near-threshold entries, patch bits
  fix_bits<<<64, 256, 0, stream>>>(x, Wq, Wk, bq, bk, pbits, flagcnt, flaglist);

  // 4) popcount-attention with MFMA PV -> hi/lo bf16
  attn_mfma<<<32 * 32, 256, 0, stream>>>(pbits, vT, oh, ol);

  // 5) out projection -> d_out
  dim3 g2(M_ROWS / 128, 1024 / 64);
  mfma_out<<<g2, 256, 0, stream>>>(oh, ol, Woh, Wol, bo, out);
}